// Round 1
// 1420.610 us; speedup vs baseline: 1.0694x; 1.0694x over previous
//
#include <hip/hip_runtime.h>
#include <cstddef>

#define V_N 49152
#define E_N 442368
#define GEPS 1e-5f
#define CO 256
#define TD 256

typedef _Float16 h16;
typedef _Float16 h8v __attribute__((ext_vector_type(8)));
typedef _Float16 h4v __attribute__((ext_vector_type(4)));
typedef _Float16 h2v __attribute__((ext_vector_type(2)));
typedef float f4v __attribute__((ext_vector_type(4)));

__device__ __forceinline__ void gload_lds16(const void* g, void* l) {
    __builtin_amdgcn_global_load_lds(
        (const __attribute__((address_space(1))) unsigned int*)g,
        (__attribute__((address_space(3))) unsigned int*)l, 16, 0, 0);
}

// ---------------- CSR build ----------------
__global__ void count_edges(const int* __restrict__ row, int* __restrict__ cnt) {
    int e = blockIdx.x * blockDim.x + threadIdx.x;
    if (e < E_N) atomicAdd(&cnt[row[e]], 1);
}

__global__ void scan_rowptr(int* __restrict__ cnt, int* __restrict__ rowptr) {
    __shared__ int part[1024];
    const int CHUNK = V_N / 1024;  // 48
    int t = threadIdx.x;
    int base = t * CHUNK;
    int s = 0;
    for (int i = 0; i < CHUNK; ++i) s += cnt[base + i];
    part[t] = s;
    __syncthreads();
    for (int off = 1; off < 1024; off <<= 1) {
        int v = part[t];
        int add = (t >= off) ? part[t - off] : 0;
        __syncthreads();
        part[t] = v + add;
        __syncthreads();
    }
    int run = (t == 0) ? 0 : part[t - 1];
    for (int i = 0; i < CHUNK; ++i) {
        int c = cnt[base + i];
        rowptr[base + i] = run;
        cnt[base + i] = run;   // cursor init for fill pass
        run += c;
    }
    if (t == 1023) rowptr[V_N] = run;
}

__global__ void fill_csr(const int* __restrict__ row, const int* __restrict__ col,
                         const float* __restrict__ vals, int* __restrict__ cursor,
                         int* __restrict__ ccol, float* __restrict__ cval) {
    int e = blockIdx.x * blockDim.x + threadIdx.x;
    if (e < E_N) {
        int r = row[e];
        int slot = atomicAdd(&cursor[r], 1);
        ccol[slot] = col[e];
        cval[slot] = vals[e];
    }
}

// ---------------- weight prep: w[k][c][f] fp32 -> wt[f][k*C+c] fp16 ----------------
__global__ void wprep(const float* __restrict__ w, h16* __restrict__ wt, int KC) {
    __shared__ float t[16][17];
    int kc = blockIdx.x * 16 + threadIdx.y;
    int f = blockIdx.y * 16 + threadIdx.x;
    t[threadIdx.y][threadIdx.x] = w[(size_t)kc * CO + f];
    __syncthreads();
    int fo = blockIdx.y * 16 + threadIdx.y;
    int kco = blockIdx.x * 16 + threadIdx.x;
    wt[(size_t)fo * KC + kco] = (h16)t[threadIdx.x][threadIdx.y];
}

// ---------------- GroupNorm stats (register accumulation, per-block partials) ----
// KEY: grid-stride is a multiple of 64, so c4 = i & cmask is CONSTANT per thread.
// Each thread belongs to exactly one group -> accumulate in registers, shuffle-
// reduce the lanes sharing a group, few LDS atomics at wave-end, plain store of
// per-block partials (no global same-address atomic contention).
template <int C>
__global__ void gn_stats2(const float* __restrict__ x, const float* __restrict__ tvec,
                          float* __restrict__ part) {
    __shared__ float ls[8], lss[8];
    int t = threadIdx.x;
    if (t < 8) { ls[t] = 0.f; lss[t] = 0.f; }
    __syncthreads();
    const int total4 = V_N * (C / 4);
    const int cmask = (C / 4) - 1;
    const int stride = gridDim.x * blockDim.x;  // multiple of 64
    int i0 = blockIdx.x * blockDim.x + t;
    const int c4 = i0 & cmask;  // constant across the loop
    float t0 = 0.f, t1 = 0.f, t2 = 0.f, t3 = 0.f;
    if (tvec) {
        t0 = tvec[c4 * 4 + 0]; t1 = tvec[c4 * 4 + 1];
        t2 = tvec[c4 * 4 + 2]; t3 = tvec[c4 * 4 + 3];
    }
    float s = 0.f, ss = 0.f;
    for (int i = i0; i < total4; i += stride) {
        float4 v = ((const float4*)x)[i];
        v.x += t0; v.y += t1; v.z += t2; v.w += t3;
        s  += v.x + v.y + v.z + v.w;
        ss += v.x * v.x + v.y * v.y + v.z * v.z + v.w * v.w;
    }
    // lanes sharing a group are consecutive: 4 (C=128) or 8 (C=256)
    constexpr int GL = (C == 128) ? 4 : 8;
#pragma unroll
    for (int off = 1; off < GL; off <<= 1) {
        s  += __shfl_xor(s, off);
        ss += __shfl_xor(ss, off);
    }
    int lane = t & 63;
    if ((lane & (GL - 1)) == 0) {
        int g = c4 >> ((C == 128) ? 2 : 3);
        atomicAdd(&ls[g], s);
        atomicAdd(&lss[g], ss);
    }
    __syncthreads();
    if (t < 16) part[blockIdx.x * 16 + t] = (t < 8) ? ls[t] : lss[t - 8];
}

#define GN_BLOCKS 512

__global__ void gn_reduce(const float* __restrict__ part, float* __restrict__ stats,
                          int nb) {
    __shared__ float acc[16];
    int t = threadIdx.x;  // 256
    if (t < 16) acc[t] = 0.f;
    __syncthreads();
    int idx = t & 15;
    float s = 0.f;
    for (int j = t >> 4; j < nb; j += 16) s += part[j * 16 + idx];
    atomicAdd(&acc[idx], s);
    __syncthreads();
    if (t < 16) stats[t] = acc[t];
}

// ---------------- GroupNorm apply + SiLU -> fp16 terms slot0 ----------------
template <int C>
__global__ void gn_apply2(const float* __restrict__ x, const float* __restrict__ tvec,
                          const float* __restrict__ stats, const float* __restrict__ gamma,
                          const float* __restrict__ beta, h16* __restrict__ dst, int ldT) {
    const float Ng = (float)V_N * (C / 8);
    const int total4 = V_N * (C / 4);
    const int cmask = (C / 4) - 1;
    const int vsh = (C == 128) ? 5 : 6;
    for (int i = blockIdx.x * blockDim.x + threadIdx.x; i < total4;
         i += gridDim.x * blockDim.x) {
        int c4 = i & cmask;
        int v = i >> vsh;
        float4 xv = ((const float4*)x)[i];
        float in[4] = {xv.x, xv.y, xv.z, xv.w};
        h4v o;
#pragma unroll
        for (int j = 0; j < 4; ++j) {
            int c = c4 * 4 + j;
            int g = c >> ((C == 128) ? 4 : 5);
            float mu = stats[g] / Ng;
            float var = stats[8 + g] / Ng - mu * mu;
            float rs = rsqrtf(var + GEPS);
            float val = in[j] + (tvec ? tvec[c] : 0.f);
            float y = (val - mu) * rs * gamma[c] + beta[c];
            y = y / (1.f + expf(-y));
            o[j] = (h16)y;
        }
        *(h4v*)&dst[(size_t)v * ldT + c4 * 4] = o;
    }
}

// ---------------- cast x -> fp16 slot0 (residual conv T0) ----------------
__global__ void cast_x(const float* __restrict__ x, h16* __restrict__ dst, int ldT) {
    int i = blockIdx.x * blockDim.x + threadIdx.x;  // V_N*32 total
    int v = i >> 5, c4 = i & 31;
    float4 xv = ((const float4*)x)[i];
    h4v o = {(h16)xv.x, (h16)xv.y, (h16)xv.z, (h16)xv.w};
    *(h4v*)&dst[(size_t)v * ldT + c4 * 4] = o;
}

// ---------------- time embedding MLP ----------------
__global__ void time_mlp(const float* __restrict__ te, const float* __restrict__ wt,
                         const float* __restrict__ bt, float* __restrict__ tvec) {
    __shared__ float s[TD];
    int f = threadIdx.x;
    float v = te[f];
    s[f] = v / (1.f + expf(-v));
    __syncthreads();
    float acc = bt[f];
    for (int t = 0; t < TD; ++t) acc += s[t] * wt[t * CO + f];
    tvec[f] = acc;
}

// ---------------- SpMV (one wave per vertex, fp16 terms) ----------------
template <int C, bool RECUR>
__global__ void spmv_w(const int* __restrict__ rowptr, const int* __restrict__ ccol,
                       const float* __restrict__ cval, const h16* __restrict__ zb,
                       const h16* __restrict__ pb, h16* __restrict__ db, int ldT) {
    constexpr int W = C / 64;   // halves per lane (2 or 4)
    int wid = threadIdx.x >> 6, lane = threadIdx.x & 63;
    int v = blockIdx.x * 4 + wid;
    int s = rowptr[v], e = rowptr[v + 1];
    float acc[W];
#pragma unroll
    for (int i = 0; i < W; ++i) acc[i] = 0.f;
    for (int j = s; j < e; ++j) {
        int cc = ccol[j];
        float val = cval[j];
        if (W == 2) {
            h2v z = *(const h2v*)&zb[(size_t)cc * ldT + lane * 2];
#pragma unroll
            for (int i = 0; i < W; ++i) acc[i] += val * (float)z[i];
        } else {
            h4v z = *(const h4v*)&zb[(size_t)cc * ldT + lane * 4];
#pragma unroll
            for (int i = 0; i < W; ++i) acc[i] += val * (float)z[i];
        }
    }
    size_t base = (size_t)v * ldT + lane * W;
    if (W == 2) {
        h2v o;
#pragma unroll
        for (int i = 0; i < W; ++i) {
            float r = RECUR ? (2.f * acc[i] - (float)pb[base + i]) : acc[i];
            o[i] = (h16)r;
        }
        *(h2v*)&db[base] = o;
    } else {
        h4v o;
#pragma unroll
        for (int i = 0; i < W; ++i) {
            float r = RECUR ? (2.f * acc[i] - (float)pb[base + i]) : acc[i];
            o[i] = (h16)r;
        }
        *(h4v*)&db[base] = o;
    }
}

// ---------------- MFMA fp16 GEMM: out[V,256] (+)= A[V, KC] * Wt^T ----------------
// A row-major stride lda; Wt[f][kc] row-major stride ldw, slice offset wofs.
template <bool ACC>
__global__ __launch_bounds__(256, 2) void gemm_f16(const h16* __restrict__ A, int lda,
                                                   const h16* __restrict__ Wt, int ldw,
                                                   int wofs, int KC,
                                                   float* __restrict__ out) {
    __shared__ h16 As[128 * 32];
    __shared__ h16 Bs[128 * 32];
    const int tid = threadIdx.x;
    const int wid = tid >> 6, lane = tid & 63;
    const int m0 = blockIdx.x * 128, n0 = blockIdx.y * 128;
    const int wm = wid & 1, wn = wid >> 1;
    const int rl = lane >> 2, q = lane & 3;
    const int fr = lane & 15, fq = lane >> 4;
    const h16* Wb = Wt + wofs;

    f4v acc[4][4];
#pragma unroll
    for (int i = 0; i < 4; ++i)
#pragma unroll
        for (int j = 0; j < 4; ++j) acc[i][j] = (f4v){0.f, 0.f, 0.f, 0.f};

    for (int k0 = 0; k0 < KC; k0 += 32) {
        __syncthreads();
#pragma unroll
        for (int j = 0; j < 2; ++j) {
            int r = wid * 32 + j * 16 + rl;
            gload_lds16(A + (size_t)(m0 + r) * lda + k0 + q * 8,
                        &As[(wid * 32 + j * 16) * 32]);
            gload_lds16(Wb + (size_t)(n0 + r) * ldw + k0 + q * 8,
                        &Bs[(wid * 32 + j * 16) * 32]);
        }
        __syncthreads();
        h8v af[4], bf[4];
#pragma unroll
        for (int i = 0; i < 4; ++i) af[i] = *(const h8v*)&As[(wm * 64 + i * 16 + fr) * 32 + fq * 8];
#pragma unroll
        for (int i = 0; i < 4; ++i) bf[i] = *(const h8v*)&Bs[(wn * 64 + i * 16 + fr) * 32 + fq * 8];
#pragma unroll
        for (int mi = 0; mi < 4; ++mi)
#pragma unroll
            for (int ni = 0; ni < 4; ++ni)
                acc[mi][ni] = __builtin_amdgcn_mfma_f32_16x16x32_f16(af[mi], bf[ni],
                                                                     acc[mi][ni], 0, 0, 0);
    }
#pragma unroll
    for (int mi = 0; mi < 4; ++mi)
#pragma unroll
        for (int ni = 0; ni < 4; ++ni)
#pragma unroll
            for (int rr = 0; rr < 4; ++rr) {
                int row = m0 + wm * 64 + mi * 16 + fq * 4 + rr;
                int col = n0 + wn * 64 + ni * 16 + fr;
                size_t idx = (size_t)row * CO + col;
                if (ACC) out[idx] += acc[mi][ni][rr];
                else out[idx] = acc[mi][ni][rr];
            }
}

// ---------------- host orchestration ----------------
static void launch_spmv(hipStream_t s, int C, bool recur, const int* rp, const int* ccol,
                        const float* cval, const h16* zb, const h16* pb, h16* db, int ldT) {
    if (C == 128) {
        if (recur) spmv_w<128, true><<<V_N / 4, 256, 0, s>>>(rp, ccol, cval, zb, pb, db, ldT);
        else       spmv_w<128, false><<<V_N / 4, 256, 0, s>>>(rp, ccol, cval, zb, pb, db, ldT);
    } else {
        if (recur) spmv_w<256, true><<<V_N / 4, 256, 0, s>>>(rp, ccol, cval, zb, pb, db, ldT);
        else       spmv_w<256, false><<<V_N / 4, 256, 0, s>>>(rp, ccol, cval, zb, pb, db, ldT);
    }
}

static void run_conv(hipStream_t s, int C, int chunk, h16* terms, const h16* Wt, int KCtot,
                     bool accOut, const int* rp, const int* ccol, const float* cval,
                     float* out) {
    int ldT = chunk * C;
    dim3 ggrid(V_N / 128, 2);
    for (int k0 = 0; k0 < 8; k0 += chunk) {
        int kend = (k0 + chunk < 8) ? k0 + chunk : 8;
        for (int k = (k0 == 0 ? 1 : k0); k < kend; ++k) {
            const h16* zb = terms + ((k - 1) % chunk) * C;
            h16* db = terms + (k % chunk) * C;
            if (k == 1) {
                launch_spmv(s, C, false, rp, ccol, cval, zb, nullptr, db, ldT);
            } else {
                const h16* pb = terms + ((k - 2) % chunk) * C;
                launch_spmv(s, C, true, rp, ccol, cval, zb, pb, db, ldT);
            }
        }
        int KC = (kend - k0) * C;
        bool acc = accOut || (k0 > 0);
        if (acc) gemm_f16<true><<<ggrid, 256, 0, s>>>(terms, ldT, Wt, KCtot, k0 * C, KC, out);
        else     gemm_f16<false><<<ggrid, 256, 0, s>>>(terms, ldT, Wt, KCtot, k0 * C, KC, out);
    }
}

extern "C" void kernel_launch(void* const* d_in, const int* in_sizes, int n_in,
                              void* d_out, int out_size, void* d_ws, size_t ws_size,
                              hipStream_t stream) {
    const float* x    = (const float*)d_in[0];
    const float* te   = (const float*)d_in[1];
    const int*   row  = (const int*)d_in[2];
    const int*   col  = (const int*)d_in[3];
    const float* vals = (const float*)d_in[4];
    const float* wres = (const float*)d_in[5];
    const float* w1   = (const float*)d_in[6];
    const float* w2   = (const float*)d_in[7];
    const float* g1   = (const float*)d_in[8];
    const float* b1   = (const float*)d_in[9];
    const float* g2   = (const float*)d_in[10];
    const float* b2   = (const float*)d_in[11];
    const float* wt   = (const float*)d_in[12];
    const float* bt   = (const float*)d_in[13];
    float* out = (float*)d_out;

    // fixed-size tail buffers
    const size_t csr_b  = (size_t)(V_N + V_N + 1) * 4 + (size_t)E_N * 8;
    const size_t wt_b   = (size_t)(1024 + 2048 + 1024) * CO * 2;
    const size_t misc_b = 4096 + (size_t)GN_BLOCKS * 16 * 4;
    auto need = [&](int ch) { return (size_t)ch * V_N * 256 * 2 + csr_b + wt_b + misc_b; };
    int chunk = (ws_size >= need(8)) ? 8 : (ws_size >= need(4)) ? 4 : 2;
    if (ws_size < need(2)) return;

    char* p = (char*)d_ws;
    h16* terms = (h16*)p;              p += (size_t)chunk * V_N * 256 * 2;
    h16* w1t = (h16*)p;                p += (size_t)1024 * CO * 2;
    h16* w2t = (h16*)p;                p += (size_t)2048 * CO * 2;
    h16* wrt = (h16*)p;                p += (size_t)1024 * CO * 2;
    int* cnt = (int*)p;                p += (size_t)V_N * 4;
    int* rp  = (int*)p;                p += (size_t)(V_N + 1) * 4;
    int* ccol = (int*)p;               p += (size_t)E_N * 4;
    float* cval = (float*)p;           p += (size_t)E_N * 4;
    float* stats = (float*)p;          p += 64;
    float* tv = (float*)p;             p += 1024;
    float* gpart = (float*)p;          p += (size_t)GN_BLOCKS * 16 * 4;

    // CSR build
    hipMemsetAsync(cnt, 0, V_N * sizeof(int), stream);
    count_edges<<<E_N / 256, 256, 0, stream>>>(row, cnt);
    scan_rowptr<<<1, 1024, 0, stream>>>(cnt, rp);
    fill_csr<<<E_N / 256, 256, 0, stream>>>(row, col, vals, cnt, ccol, cval);

    // weight prep
    wprep<<<dim3(1024 / 16, 16), dim3(16, 16), 0, stream>>>(w1, w1t, 1024);
    wprep<<<dim3(2048 / 16, 16), dim3(16, 16), 0, stream>>>(w2, w2t, 2048);
    wprep<<<dim3(1024 / 16, 16), dim3(16, 16), 0, stream>>>(wres, wrt, 1024);

    // time embedding
    time_mlp<<<1, 256, 0, stream>>>(te, wt, bt, tv);

    // ---- GN1 + SiLU -> terms slot0 ----
    gn_stats2<128><<<GN_BLOCKS, 256, 0, stream>>>(x, nullptr, gpart);
    gn_reduce<<<1, 256, 0, stream>>>(gpart, stats, GN_BLOCKS);
    gn_apply2<128><<<2048, 256, 0, stream>>>(x, nullptr, stats, g1, b1, terms, chunk * 128);

    // ---- conv1 -> d_out (h1) ----
    run_conv(stream, 128, chunk, terms, w1t, 1024, false, rp, ccol, cval, out);

    // ---- GN2(h1 + tv) + SiLU -> terms slot0 ----
    gn_stats2<256><<<GN_BLOCKS, 256, 0, stream>>>(out, tv, gpart);
    gn_reduce<<<1, 256, 0, stream>>>(gpart, stats, GN_BLOCKS);
    gn_apply2<256><<<2048, 256, 0, stream>>>(out, tv, stats, g2, b2, terms, chunk * 256);

    // ---- conv2 -> d_out (overwrite) ----
    run_conv(stream, 256, chunk, terms, w2t, 2048, false, rp, ccol, cval, out);

    // ---- residual conv on raw x -> accumulate into d_out ----
    cast_x<<<V_N * 32 / 256, 256, 0, stream>>>(x, terms, chunk * 128);
    run_conv(stream, 128, chunk, terms, wrt, 1024, true, rp, ccol, cval, out);
}

// Round 2
// 949.837 us; speedup vs baseline: 1.5994x; 1.4956x over previous
//
#include <hip/hip_runtime.h>
#include <cstddef>

#define V_N 49152
#define E_N 442368
#define GEPS 1e-5f
#define CO 256
#define TD 256

typedef _Float16 h16;
typedef _Float16 h8v __attribute__((ext_vector_type(8)));
typedef _Float16 h4v __attribute__((ext_vector_type(4)));
typedef float f4v __attribute__((ext_vector_type(4)));

__device__ __forceinline__ void gload_lds16(const void* g, void* l) {
    __builtin_amdgcn_global_load_lds(
        (const __attribute__((address_space(1))) unsigned int*)g,
        (__attribute__((address_space(3))) unsigned int*)l, 16, 0, 0);
}

// ---------------- CSR build ----------------
__global__ void count_edges(const int* __restrict__ row, int* __restrict__ cnt) {
    int e = blockIdx.x * blockDim.x + threadIdx.x;
    if (e < E_N) atomicAdd(&cnt[row[e]], 1);
}

__global__ void scan_rowptr(int* __restrict__ cnt, int* __restrict__ rowptr) {
    __shared__ int part[1024];
    const int CHUNK = V_N / 1024;  // 48
    int t = threadIdx.x;
    int base = t * CHUNK;
    int s = 0;
    for (int i = 0; i < CHUNK; ++i) s += cnt[base + i];
    part[t] = s;
    __syncthreads();
    for (int off = 1; off < 1024; off <<= 1) {
        int v = part[t];
        int add = (t >= off) ? part[t - off] : 0;
        __syncthreads();
        part[t] = v + add;
        __syncthreads();
    }
    int run = (t == 0) ? 0 : part[t - 1];
    for (int i = 0; i < CHUNK; ++i) {
        int c = cnt[base + i];
        rowptr[base + i] = run;
        cnt[base + i] = run;   // cursor init for fill pass
        run += c;
    }
    if (t == 1023) rowptr[V_N] = run;
}

// packed edge: {col, val bits} -> one 8B load per edge in spmv
__global__ void fill_csr(const int* __restrict__ row, const int* __restrict__ col,
                         const float* __restrict__ vals, int* __restrict__ cursor,
                         int2* __restrict__ ep) {
    int e = blockIdx.x * blockDim.x + threadIdx.x;
    if (e < E_N) {
        int r = row[e];
        int slot = atomicAdd(&cursor[r], 1);
        ep[slot] = make_int2(col[e], __float_as_int(vals[e]));
    }
}

// ---------------- weight prep: w[k][c][f] fp32 -> wt[f][k*C+c] fp16 ----------------
__global__ void wprep(const float* __restrict__ w, h16* __restrict__ wt, int KC) {
    __shared__ float t[16][17];
    int kc = blockIdx.x * 16 + threadIdx.y;
    int f = blockIdx.y * 16 + threadIdx.x;
    t[threadIdx.y][threadIdx.x] = w[(size_t)kc * CO + f];
    __syncthreads();
    int fo = blockIdx.y * 16 + threadIdx.y;
    int kco = blockIdx.x * 16 + threadIdx.x;
    wt[(size_t)fo * KC + kco] = (h16)t[threadIdx.x][threadIdx.y];
}

// ---------------- GroupNorm stats (register accumulation, per-block partials) ----
template <int C>
__global__ void gn_stats2(const float* __restrict__ x, const float* __restrict__ tvec,
                          float* __restrict__ part) {
    __shared__ float ls[8], lss[8];
    int t = threadIdx.x;
    if (t < 8) { ls[t] = 0.f; lss[t] = 0.f; }
    __syncthreads();
    const int total4 = V_N * (C / 4);
    const int cmask = (C / 4) - 1;
    const int stride = gridDim.x * blockDim.x;  // multiple of 64
    int i0 = blockIdx.x * blockDim.x + t;
    const int c4 = i0 & cmask;  // constant across the loop
    float t0 = 0.f, t1 = 0.f, t2 = 0.f, t3 = 0.f;
    if (tvec) {
        t0 = tvec[c4 * 4 + 0]; t1 = tvec[c4 * 4 + 1];
        t2 = tvec[c4 * 4 + 2]; t3 = tvec[c4 * 4 + 3];
    }
    float s = 0.f, ss = 0.f;
    for (int i = i0; i < total4; i += stride) {
        float4 v = ((const float4*)x)[i];
        v.x += t0; v.y += t1; v.z += t2; v.w += t3;
        s  += v.x + v.y + v.z + v.w;
        ss += v.x * v.x + v.y * v.y + v.z * v.z + v.w * v.w;
    }
    constexpr int GL = (C == 128) ? 4 : 8;
#pragma unroll
    for (int off = 1; off < GL; off <<= 1) {
        s  += __shfl_xor(s, off);
        ss += __shfl_xor(ss, off);
    }
    int lane = t & 63;
    if ((lane & (GL - 1)) == 0) {
        int g = c4 >> ((C == 128) ? 2 : 3);
        atomicAdd(&ls[g], s);
        atomicAdd(&lss[g], ss);
    }
    __syncthreads();
    if (t < 16) part[blockIdx.x * 16 + t] = (t < 8) ? ls[t] : lss[t - 8];
}

#define GN_BLOCKS 512

__global__ void gn_reduce(const float* __restrict__ part, float* __restrict__ stats,
                          int nb) {
    __shared__ float acc[16];
    int t = threadIdx.x;  // 256
    if (t < 16) acc[t] = 0.f;
    __syncthreads();
    int idx = t & 15;
    float s = 0.f;
    for (int j = t >> 4; j < nb; j += 16) s += part[j * 16 + idx];
    atomicAdd(&acc[idx], s);
    __syncthreads();
    if (t < 16) stats[t] = acc[t];
}

// ---------------- GN1 apply + SiLU -> slot0[0..128), raw cast -> slot0[128..256) ----
__global__ void gn1_apply(const float* __restrict__ x, const float* __restrict__ stats,
                          const float* __restrict__ gamma, const float* __restrict__ beta,
                          h16* __restrict__ dst, int ldT) {
    const float Ng = (float)V_N * 16.f;   // C=128: V*C/8
    const int total4 = V_N * 32;
    for (int i = blockIdx.x * blockDim.x + threadIdx.x; i < total4;
         i += gridDim.x * blockDim.x) {
        int c4 = i & 31;
        int v = i >> 5;
        float4 xv = ((const float4*)x)[i];
        float in[4] = {xv.x, xv.y, xv.z, xv.w};
        h4v o, oc;
#pragma unroll
        for (int j = 0; j < 4; ++j) {
            int c = c4 * 4 + j;
            int g = c >> 4;
            float mu = stats[g] / Ng;
            float var = stats[8 + g] / Ng - mu * mu;
            float rs = rsqrtf(var + GEPS);
            float y = (in[j] - mu) * rs * gamma[c] + beta[c];
            y = y / (1.f + expf(-y));
            o[j] = (h16)y;
            oc[j] = (h16)in[j];
        }
        size_t base = (size_t)v * ldT + c4 * 4;
        *(h4v*)&dst[base] = o;
        *(h4v*)&dst[base + 128] = oc;
    }
}

// ---------------- GN2 apply + SiLU -> fp16 slot0 (full 256) ----------------
__global__ void gn2_apply(const float* __restrict__ x, const float* __restrict__ tvec,
                          const float* __restrict__ stats, const float* __restrict__ gamma,
                          const float* __restrict__ beta, h16* __restrict__ dst, int ldT) {
    const float Ng = (float)V_N * 32.f;   // C=256: V*C/8
    const int total4 = V_N * 64;
    for (int i = blockIdx.x * blockDim.x + threadIdx.x; i < total4;
         i += gridDim.x * blockDim.x) {
        int c4 = i & 63;
        int v = i >> 6;
        float4 xv = ((const float4*)x)[i];
        float in[4] = {xv.x, xv.y, xv.z, xv.w};
        h4v o;
#pragma unroll
        for (int j = 0; j < 4; ++j) {
            int c = c4 * 4 + j;
            int g = c >> 5;
            float mu = stats[g] / Ng;
            float var = stats[8 + g] / Ng - mu * mu;
            float rs = rsqrtf(var + GEPS);
            float val = in[j] + tvec[c];
            float y = (val - mu) * rs * gamma[c] + beta[c];
            y = y / (1.f + expf(-y));
            o[j] = (h16)y;
        }
        *(h4v*)&dst[(size_t)v * ldT + c4 * 4] = o;
    }
}

// ---------------- time embedding MLP ----------------
__global__ void time_mlp(const float* __restrict__ te, const float* __restrict__ wt,
                         const float* __restrict__ bt, float* __restrict__ tvec) {
    __shared__ float s[TD];
    int f = threadIdx.x;
    float v = te[f];
    s[f] = v / (1.f + expf(-v));
    __syncthreads();
    float acc = bt[f];
    for (int t = 0; t < TD; ++t) acc += s[t] * wt[t * CO + f];
    tvec[f] = acc;
}

// ---------------- SpMV C=256: half-wave per edge, 16B loads, 2 edges/iter ----------
template <bool RECUR>
__global__ void spmv2(const int* __restrict__ rowptr, const int2* __restrict__ ep,
                      const h16* __restrict__ zb, const h16* __restrict__ pb,
                      h16* __restrict__ db, int ldT) {
    int wid = threadIdx.x >> 6, lane = threadIdx.x & 63;
    int v = blockIdx.x * 4 + wid;
    int s = rowptr[v], e = rowptr[v + 1];
    int half = lane >> 5, hl = lane & 31;
    float acc[8];
#pragma unroll
    for (int i = 0; i < 8; ++i) acc[i] = 0.f;
    for (int j = s; j < e; j += 2) {
        int jj = j + half;
        int jm = (jj < e) ? jj : (e - 1);
        int2 p = ep[jm];
        float val = (jj < e) ? __int_as_float(p.y) : 0.f;
        h8v z = *(const h8v*)&zb[(size_t)p.x * ldT + hl * 8];
#pragma unroll
        for (int i = 0; i < 8; ++i) acc[i] += val * (float)z[i];
    }
#pragma unroll
    for (int i = 0; i < 8; ++i) acc[i] += __shfl_xor(acc[i], 32);
    if (half == 0) {
        size_t base = (size_t)v * ldT + hl * 8;
        h8v o;
        if (RECUR) {
            h8v pv = *(const h8v*)&pb[base];
#pragma unroll
            for (int i = 0; i < 8; ++i) o[i] = (h16)(2.f * acc[i] - (float)pv[i]);
        } else {
#pragma unroll
            for (int i = 0; i < 8; ++i) o[i] = (h16)acc[i];
        }
        *(h8v*)&db[base] = o;
    }
}

// ---------------- MFMA fp16 GEMM: out[V,256] (+)= A[V, KC(remapped)] * Wt^T -------
// Tile 128x256, one block covers full N (A fetched once). XOR slot swizzle via
// pre-swizzled global source (global_load_lds writes linearly).
// A logical col kc maps to buffer col (kc>>ksh)*256 + (kc & ((1<<ksh)-1)).
template <bool ACC>
__global__ __launch_bounds__(256, 2) void gemm_f16(const h16* __restrict__ A, int lda,
                                                   const h16* __restrict__ Wt, int ldw,
                                                   int wofs, int KC, int ksh,
                                                   float* __restrict__ out) {
    __shared__ h16 As[128 * 32];
    __shared__ h16 Bs[256 * 32];
    const int tid = threadIdx.x;
    const int wid = tid >> 6, lane = tid & 63;
    const int m0 = blockIdx.x * 128;
    const int wm = wid & 1, wn = wid >> 1;
    const int fr = lane & 15, fq = lane >> 4;
    const int rl = lane >> 2;                              // row within 16-group
    const int qs = (lane & 3) ^ ((lane >> 3) & 3);         // swizzled source slot
    const int kmsk = (1 << ksh) - 1;
    const h16* Wb = Wt + wofs;

    f4v acc[4][8];
#pragma unroll
    for (int i = 0; i < 4; ++i)
#pragma unroll
        for (int n = 0; n < 8; ++n) acc[i][n] = (f4v){0.f, 0.f, 0.f, 0.f};

    for (int k0 = 0; k0 < KC; k0 += 32) {
        int ca = (((k0 >> ksh) << 8) | (k0 & kmsk)) + qs * 8;  // A buffer col
        int cb = k0 + qs * 8;                                  // W col
        __syncthreads();
#pragma unroll
        for (int j = 0; j < 2; ++j) {
            int rbase = wid * 32 + j * 16;
            gload_lds16(A + (size_t)(m0 + rbase + rl) * lda + ca, &As[rbase * 32]);
        }
#pragma unroll
        for (int j = 0; j < 4; ++j) {
            int rbase = wid * 64 + j * 16;
            gload_lds16(Wb + (size_t)(rbase + rl) * ldw + cb, &Bs[rbase * 32]);
        }
        __syncthreads();
        const int slot = (fq ^ ((fr >> 1) & 3)) * 8;
        h8v af[4], bf[8];
#pragma unroll
        for (int i = 0; i < 4; ++i)
            af[i] = *(const h8v*)&As[(wm * 64 + i * 16 + fr) * 32 + slot];
#pragma unroll
        for (int n = 0; n < 8; ++n)
            bf[n] = *(const h8v*)&Bs[(wn * 128 + n * 16 + fr) * 32 + slot];
#pragma unroll
        for (int i = 0; i < 4; ++i)
#pragma unroll
            for (int n = 0; n < 8; ++n)
                acc[i][n] = __builtin_amdgcn_mfma_f32_16x16x32_f16(af[i], bf[n],
                                                                   acc[i][n], 0, 0, 0);
    }
#pragma unroll
    for (int i = 0; i < 4; ++i)
#pragma unroll
        for (int n = 0; n < 8; ++n)
#pragma unroll
            for (int rr = 0; rr < 4; ++rr) {
                int row = m0 + wm * 64 + i * 16 + fq * 4 + rr;
                int col = wn * 128 + n * 16 + fr;
                size_t idx = (size_t)row * CO + col;
                if (ACC) out[idx] += acc[i][n][rr];
                else out[idx] = acc[i][n][rr];
            }
}

// ---------------- host orchestration ----------------
static void launch_gemm(hipStream_t s, bool acc, const h16* A, int lda, const h16* Wt,
                        int ldw, int wofs, int KC, int ksh, float* out) {
    dim3 g(V_N / 128);
    if (acc) gemm_f16<true><<<g, 256, 0, s>>>(A, lda, Wt, ldw, wofs, KC, ksh, out);
    else     gemm_f16<false><<<g, 256, 0, s>>>(A, lda, Wt, ldw, wofs, KC, ksh, out);
}

static void chain_spmv(hipStream_t s, int chunk, int k0, int kend, h16* terms, int ldT,
                       const int* rp, const int2* ep) {
    for (int k = (k0 == 0 ? 1 : k0); k < kend; ++k) {
        const h16* zb = terms + ((k - 1) % chunk) * 256;
        h16* db = terms + (k % chunk) * 256;
        if (k == 1) {
            spmv2<false><<<V_N / 4, 256, 0, s>>>(rp, ep, zb, nullptr, db, ldT);
        } else {
            const h16* pb = terms + ((k - 2) % chunk) * 256;
            spmv2<true><<<V_N / 4, 256, 0, s>>>(rp, ep, zb, pb, db, ldT);
        }
    }
}

extern "C" void kernel_launch(void* const* d_in, const int* in_sizes, int n_in,
                              void* d_out, int out_size, void* d_ws, size_t ws_size,
                              hipStream_t stream) {
    const float* x    = (const float*)d_in[0];
    const float* te   = (const float*)d_in[1];
    const int*   row  = (const int*)d_in[2];
    const int*   col  = (const int*)d_in[3];
    const float* vals = (const float*)d_in[4];
    const float* wres = (const float*)d_in[5];
    const float* w1   = (const float*)d_in[6];
    const float* w2   = (const float*)d_in[7];
    const float* g1   = (const float*)d_in[8];
    const float* b1   = (const float*)d_in[9];
    const float* g2   = (const float*)d_in[10];
    const float* b2   = (const float*)d_in[11];
    const float* wt   = (const float*)d_in[12];
    const float* bt   = (const float*)d_in[13];
    float* out = (float*)d_out;

    const size_t slot_b = (size_t)V_N * 256 * 2;          // 25.2 MB per k-slot
    const size_t res_b  = (size_t)V_N * 256 * 4;          // 50.3 MB
    const size_t csr_b  = (size_t)(V_N + V_N + 1) * 4 + (size_t)E_N * 8;
    const size_t wt_b   = (size_t)(1024 + 2048 + 1024) * CO * 2;
    const size_t misc_b = 8192 + (size_t)GN_BLOCKS * 16 * 4;
    auto need = [&](int ch) { return (size_t)ch * slot_b + res_b + csr_b + wt_b + misc_b; };
    int chunk = (ws_size >= need(8)) ? 8 : (ws_size >= need(4)) ? 4 : 2;
    if (ws_size < need(2)) return;
    const int ldT = chunk * 256;

    char* p = (char*)d_ws;
    h16* terms = (h16*)p;              p += (size_t)chunk * slot_b;
    float* resbuf = (float*)p;         p += res_b;
    h16* w1t = (h16*)p;                p += (size_t)1024 * CO * 2;
    h16* w2t = (h16*)p;                p += (size_t)2048 * CO * 2;
    h16* wrt = (h16*)p;                p += (size_t)1024 * CO * 2;
    int* cnt = (int*)p;                p += (size_t)V_N * 4;
    int* rp  = (int*)p;                p += (size_t)(V_N + 1) * 4;
    int2* ep = (int2*)p;               p += (size_t)E_N * 8;
    float* stats = (float*)p;          p += 64;
    float* tv = (float*)p;             p += 1024;
    float* gpart = (float*)p;          p += (size_t)GN_BLOCKS * 16 * 4;

    // CSR build
    hipMemsetAsync(cnt, 0, V_N * sizeof(int), stream);
    count_edges<<<E_N / 256, 256, 0, stream>>>(row, cnt);
    scan_rowptr<<<1, 1024, 0, stream>>>(cnt, rp);
    fill_csr<<<E_N / 256, 256, 0, stream>>>(row, col, vals, cnt, ep);

    // weight prep
    wprep<<<dim3(1024 / 16, 16), dim3(16, 16), 0, stream>>>(w1, w1t, 1024);
    wprep<<<dim3(2048 / 16, 16), dim3(16, 16), 0, stream>>>(w2, w2t, 2048);
    wprep<<<dim3(1024 / 16, 16), dim3(16, 16), 0, stream>>>(wres, wrt, 1024);

    // time embedding
    time_mlp<<<1, 256, 0, stream>>>(te, wt, bt, tv);

    // ---- GN1 + SiLU -> slot0 [gn | raw x] (merged conv1+res chain, C=256) ----
    gn_stats2<128><<<GN_BLOCKS, 256, 0, stream>>>(x, nullptr, gpart);
    gn_reduce<<<1, 256, 0, stream>>>(gpart, stats, GN_BLOCKS);
    gn1_apply<<<2048, 256, 0, stream>>>(x, stats, g1, b1, terms, ldT);

    // ---- merged chain: 7 SpMV (C=256) + conv1 gemm (gn half) + res gemm (x half) ----
    for (int k0 = 0; k0 < 8; k0 += chunk) {
        int kend = (k0 + chunk < 8) ? k0 + chunk : 8;
        chain_spmv(stream, chunk, k0, kend, terms, ldT, rp, ep);
        int KC = (kend - k0) * 128;
        bool acc = (k0 > 0);
        launch_gemm(stream, acc, terms,       ldT, w1t, 1024, k0 * 128, KC, 7, out);
        launch_gemm(stream, acc, terms + 128, ldT, wrt, 1024, k0 * 128, KC, 7, resbuf);
    }

    // ---- GN2(h1 + tv) + SiLU -> terms slot0 (full 256) ----
    gn_stats2<256><<<GN_BLOCKS, 256, 0, stream>>>(out, tv, gpart);
    gn_reduce<<<1, 256, 0, stream>>>(gpart, stats, GN_BLOCKS);
    gn2_apply<<<2048, 256, 0, stream>>>(out, tv, stats, g2, b2, terms, ldT);

    // ---- preload residual into d_out, then conv2 accumulates on top ----
    hipMemcpyAsync(out, resbuf, res_b, hipMemcpyDeviceToDevice, stream);

    // ---- conv2 chain: 7 SpMV (C=256) + gemm (identity remap), ACC onto residual ----
    for (int k0 = 0; k0 < 8; k0 += chunk) {
        int kend = (k0 + chunk < 8) ? k0 + chunk : 8;
        chain_spmv(stream, chunk, k0, kend, terms, ldT, rp, ep);
        int KC = (kend - k0) * 256;
        launch_gemm(stream, true, terms, ldT, w2t, 2048, k0 * 256, KC, 8, out);
    }
}

// Round 3
// 882.736 us; speedup vs baseline: 1.7210x; 1.0760x over previous
//
#include <hip/hip_runtime.h>
#include <cstddef>

#define V_N 49152
#define E_N 442368
#define GEPS 1e-5f
#define CO 256
#define TD 256

typedef _Float16 h16;
typedef _Float16 h8v __attribute__((ext_vector_type(8)));
typedef _Float16 h4v __attribute__((ext_vector_type(4)));
typedef float f4v __attribute__((ext_vector_type(4)));

__device__ __forceinline__ void gload_lds16(const void* g, void* l) {
    __builtin_amdgcn_global_load_lds(
        (const __attribute__((address_space(1))) unsigned int*)g,
        (__attribute__((address_space(3))) unsigned int*)l, 16, 0, 0);
}

// ---------------- CSR build ----------------
__global__ void count_edges(const int* __restrict__ row, int* __restrict__ cnt) {
    int e = blockIdx.x * blockDim.x + threadIdx.x;
    if (e < E_N) atomicAdd(&cnt[row[e]], 1);
}

__global__ void scan_rowptr(int* __restrict__ cnt, int* __restrict__ rowptr) {
    __shared__ int part[1024];
    const int CHUNK = V_N / 1024;  // 48
    int t = threadIdx.x;
    int base = t * CHUNK;
    int s = 0;
    for (int i = 0; i < CHUNK; ++i) s += cnt[base + i];
    part[t] = s;
    __syncthreads();
    for (int off = 1; off < 1024; off <<= 1) {
        int v = part[t];
        int add = (t >= off) ? part[t - off] : 0;
        __syncthreads();
        part[t] = v + add;
        __syncthreads();
    }
    int run = (t == 0) ? 0 : part[t - 1];
    for (int i = 0; i < CHUNK; ++i) {
        int c = cnt[base + i];
        rowptr[base + i] = run;
        cnt[base + i] = run;   // cursor init for fill pass
        run += c;
    }
    if (t == 1023) rowptr[V_N] = run;
}

// packed edge: {col, val bits} -> one 8B load per edge in spmv
__global__ void fill_csr(const int* __restrict__ row, const int* __restrict__ col,
                         const float* __restrict__ vals, int* __restrict__ cursor,
                         int2* __restrict__ ep) {
    int e = blockIdx.x * blockDim.x + threadIdx.x;
    if (e < E_N) {
        int r = row[e];
        int slot = atomicAdd(&cursor[r], 1);
        ep[slot] = make_int2(col[e], __float_as_int(vals[e]));
    }
}

// ---------------- weight prep: w[k][c][f] fp32 -> wt[f][k*C+c] fp16 ----------------
__global__ void wprep(const float* __restrict__ w, h16* __restrict__ wt, int KC) {
    __shared__ float t[16][17];
    int kc = blockIdx.x * 16 + threadIdx.y;
    int f = blockIdx.y * 16 + threadIdx.x;
    t[threadIdx.y][threadIdx.x] = w[(size_t)kc * CO + f];
    __syncthreads();
    int fo = blockIdx.y * 16 + threadIdx.y;
    int kco = blockIdx.x * 16 + threadIdx.x;
    wt[(size_t)fo * KC + kco] = (h16)t[threadIdx.x][threadIdx.y];
}

// ---------------- GroupNorm stats (register accumulation, per-block partials) ----
template <int C>
__global__ void gn_stats2(const float* __restrict__ x, const float* __restrict__ tvec,
                          float* __restrict__ part) {
    __shared__ float ls[8], lss[8];
    int t = threadIdx.x;
    if (t < 8) { ls[t] = 0.f; lss[t] = 0.f; }
    __syncthreads();
    const int total4 = V_N * (C / 4);
    const int cmask = (C / 4) - 1;
    const int stride = gridDim.x * blockDim.x;  // multiple of 64
    int i0 = blockIdx.x * blockDim.x + t;
    const int c4 = i0 & cmask;  // constant across the loop
    float t0 = 0.f, t1 = 0.f, t2 = 0.f, t3 = 0.f;
    if (tvec) {
        t0 = tvec[c4 * 4 + 0]; t1 = tvec[c4 * 4 + 1];
        t2 = tvec[c4 * 4 + 2]; t3 = tvec[c4 * 4 + 3];
    }
    float s = 0.f, ss = 0.f;
    for (int i = i0; i < total4; i += stride) {
        float4 v = ((const float4*)x)[i];
        v.x += t0; v.y += t1; v.z += t2; v.w += t3;
        s  += v.x + v.y + v.z + v.w;
        ss += v.x * v.x + v.y * v.y + v.z * v.z + v.w * v.w;
    }
    constexpr int GL = (C == 128) ? 4 : 8;
#pragma unroll
    for (int off = 1; off < GL; off <<= 1) {
        s  += __shfl_xor(s, off);
        ss += __shfl_xor(ss, off);
    }
    int lane = t & 63;
    if ((lane & (GL - 1)) == 0) {
        int g = c4 >> ((C == 128) ? 2 : 3);
        atomicAdd(&ls[g], s);
        atomicAdd(&lss[g], ss);
    }
    __syncthreads();
    if (t < 16) part[blockIdx.x * 16 + t] = (t < 8) ? ls[t] : lss[t - 8];
}

#define GN_BLOCKS 512

__global__ void gn_reduce(const float* __restrict__ part, float* __restrict__ stats,
                          int nb) {
    __shared__ float acc[16];
    int t = threadIdx.x;  // 256
    if (t < 16) acc[t] = 0.f;
    __syncthreads();
    int idx = t & 15;
    float s = 0.f;
    for (int j = t >> 4; j < nb; j += 16) s += part[j * 16 + idx];
    atomicAdd(&acc[idx], s);
    __syncthreads();
    if (t < 16) stats[t] = acc[t];
}

// ---------------- GN1 apply + SiLU -> slot0[0..128), raw cast -> slot0[128..256) ----
__global__ void gn1_apply(const float* __restrict__ x, const float* __restrict__ stats,
                          const float* __restrict__ gamma, const float* __restrict__ beta,
                          h16* __restrict__ dst, int ldT) {
    const float Ng = (float)V_N * 16.f;   // C=128: V*C/8
    const int total4 = V_N * 32;
    for (int i = blockIdx.x * blockDim.x + threadIdx.x; i < total4;
         i += gridDim.x * blockDim.x) {
        int c4 = i & 31;
        int v = i >> 5;
        float4 xv = ((const float4*)x)[i];
        float in[4] = {xv.x, xv.y, xv.z, xv.w};
        h4v o, oc;
#pragma unroll
        for (int j = 0; j < 4; ++j) {
            int c = c4 * 4 + j;
            int g = c >> 4;
            float mu = stats[g] / Ng;
            float var = stats[8 + g] / Ng - mu * mu;
            float rs = rsqrtf(var + GEPS);
            float y = (in[j] - mu) * rs * gamma[c] + beta[c];
            y = y / (1.f + expf(-y));
            o[j] = (h16)y;
            oc[j] = (h16)in[j];
        }
        size_t base = (size_t)v * ldT + c4 * 4;
        *(h4v*)&dst[base] = o;
        *(h4v*)&dst[base + 128] = oc;
    }
}

// ---------------- GN2 apply + SiLU -> fp16 slot0 (full 256) ----------------
__global__ void gn2_apply(const float* __restrict__ x, const float* __restrict__ tvec,
                          const float* __restrict__ stats, const float* __restrict__ gamma,
                          const float* __restrict__ beta, h16* __restrict__ dst, int ldT) {
    const float Ng = (float)V_N * 32.f;   // C=256: V*C/8
    const int total4 = V_N * 64;
    for (int i = blockIdx.x * blockDim.x + threadIdx.x; i < total4;
         i += gridDim.x * blockDim.x) {
        int c4 = i & 63;
        int v = i >> 6;
        float4 xv = ((const float4*)x)[i];
        float in[4] = {xv.x, xv.y, xv.z, xv.w};
        h4v o;
#pragma unroll
        for (int j = 0; j < 4; ++j) {
            int c = c4 * 4 + j;
            int g = c >> 5;
            float mu = stats[g] / Ng;
            float var = stats[8 + g] / Ng - mu * mu;
            float rs = rsqrtf(var + GEPS);
            float val = in[j] + tvec[c];
            float y = (val - mu) * rs * gamma[c] + beta[c];
            y = y / (1.f + expf(-y));
            o[j] = (h16)y;
        }
        *(h4v*)&dst[(size_t)v * ldT + c4 * 4] = o;
    }
}

// ---------------- time embedding MLP ----------------
__global__ void time_mlp(const float* __restrict__ te, const float* __restrict__ wt,
                         const float* __restrict__ bt, float* __restrict__ tvec) {
    __shared__ float s[TD];
    int f = threadIdx.x;
    float v = te[f];
    s[f] = v / (1.f + expf(-v));
    __syncthreads();
    float acc = bt[f];
    for (int t = 0; t < TD; ++t) acc += s[t] * wt[t * CO + f];
    tvec[f] = acc;
}

// ---------------- SpMV C=256: half-wave per edge, 16B loads, 4 edges in flight ----
template <bool RECUR>
__global__ void spmv2(const int* __restrict__ rowptr, const int2* __restrict__ ep,
                      const h16* __restrict__ zb, const h16* __restrict__ pb,
                      h16* __restrict__ db, int ldT) {
    int wid = threadIdx.x >> 6, lane = threadIdx.x & 63;
    int v = blockIdx.x * 4 + wid;
    int s = rowptr[v], e = rowptr[v + 1];
    int half = lane >> 5, hl = lane & 31;
    float acc[8];
#pragma unroll
    for (int i = 0; i < 8; ++i) acc[i] = 0.f;
    for (int j = s; j < e; j += 4) {
        int j0 = j + half, j1 = j + half + 2;
        int2 p0 = ep[(j0 < e) ? j0 : (e - 1)];
        int2 p1 = ep[(j1 < e) ? j1 : (e - 1)];
        float v0 = (j0 < e) ? __int_as_float(p0.y) : 0.f;
        float v1 = (j1 < e) ? __int_as_float(p1.y) : 0.f;
        h8v z0 = *(const h8v*)&zb[(size_t)p0.x * ldT + hl * 8];
        h8v z1 = *(const h8v*)&zb[(size_t)p1.x * ldT + hl * 8];
#pragma unroll
        for (int i = 0; i < 8; ++i) acc[i] += v0 * (float)z0[i];
#pragma unroll
        for (int i = 0; i < 8; ++i) acc[i] += v1 * (float)z1[i];
    }
#pragma unroll
    for (int i = 0; i < 8; ++i) acc[i] += __shfl_xor(acc[i], 32);
    if (half == 0) {
        size_t base = (size_t)v * ldT + hl * 8;
        h8v o;
        if (RECUR) {
            h8v pv = *(const h8v*)&pb[base];
#pragma unroll
            for (int i = 0; i < 8; ++i) o[i] = (h16)(2.f * acc[i] - (float)pv[i]);
        } else {
#pragma unroll
            for (int i = 0; i < 8; ++i) o[i] = (h16)acc[i];
        }
        *(h8v*)&db[base] = o;
    }
}

// ---------------- MFMA fp16 GEMM: 64x256 tile, grid 768 = 3 blocks/CU ----------
// MODE: 0 = store, 1 = accumulate, 2 = out = bias + acc (residual fuse).
// DUAL: blockIdx.y selects {A+0,Wt,out} vs {A+128,Wt2,out2} (conv1 + res fused).
// A logical col kc maps to buffer col (kc>>ksh)*256 + (kc & ((1<<ksh)-1)).
template <int MODE, bool DUAL>
__global__ __launch_bounds__(256, 3) void gemm_f16(
    const h16* __restrict__ A, int lda, const h16* __restrict__ Wt,
    const h16* __restrict__ Wt2, int ldw, int wofs, int KC, int ksh,
    const float* __restrict__ bias, float* __restrict__ out,
    float* __restrict__ out2) {
    __shared__ h16 As[64 * 32];
    __shared__ h16 Bs[256 * 32];
    if (DUAL && blockIdx.y) { A += 128; Wt = Wt2; out = out2; }
    const int tid = threadIdx.x;
    const int wid = tid >> 6, lane = tid & 63;
    const int m0 = blockIdx.x * 64;
    const int fr = lane & 15, fq = lane >> 4;
    const int rl = lane >> 2;                              // row within 16-group
    const int qs = (lane & 3) ^ ((lane >> 3) & 3);         // swizzled source slot
    const int kmsk = (1 << ksh) - 1;
    const h16* Wb = Wt + wofs;

    f4v acc[4][4];
#pragma unroll
    for (int i = 0; i < 4; ++i)
#pragma unroll
        for (int n = 0; n < 4; ++n) acc[i][n] = (f4v){0.f, 0.f, 0.f, 0.f};

    for (int k0 = 0; k0 < KC; k0 += 32) {
        int ca = (((k0 >> ksh) << 8) | (k0 & kmsk)) + qs * 8;  // A buffer col
        int cb = k0 + qs * 8;                                  // W col
        __syncthreads();
        gload_lds16(A + (size_t)(m0 + wid * 16 + rl) * lda + ca, &As[(wid * 16) * 32]);
#pragma unroll
        for (int j = 0; j < 4; ++j) {
            int rbase = wid * 64 + j * 16;
            gload_lds16(Wb + (size_t)(rbase + rl) * ldw + cb, &Bs[rbase * 32]);
        }
        __syncthreads();
        const int slot = (fq ^ ((fr >> 1) & 3)) * 8;
        h8v af[4], bf[4];
#pragma unroll
        for (int i = 0; i < 4; ++i)
            af[i] = *(const h8v*)&As[(i * 16 + fr) * 32 + slot];
#pragma unroll
        for (int n = 0; n < 4; ++n)
            bf[n] = *(const h8v*)&Bs[(wid * 64 + n * 16 + fr) * 32 + slot];
#pragma unroll
        for (int i = 0; i < 4; ++i)
#pragma unroll
            for (int n = 0; n < 4; ++n)
                acc[i][n] = __builtin_amdgcn_mfma_f32_16x16x32_f16(af[i], bf[n],
                                                                   acc[i][n], 0, 0, 0);
    }
#pragma unroll
    for (int i = 0; i < 4; ++i)
#pragma unroll
        for (int n = 0; n < 4; ++n)
#pragma unroll
            for (int rr = 0; rr < 4; ++rr) {
                int row = m0 + i * 16 + fq * 4 + rr;
                int col = wid * 64 + n * 16 + fr;
                size_t idx = (size_t)row * CO + col;
                if (MODE == 0) out[idx] = acc[i][n][rr];
                else if (MODE == 1) out[idx] += acc[i][n][rr];
                else out[idx] = bias[idx] + acc[i][n][rr];
            }
}

// ---------------- host orchestration ----------------
static void chain_spmv(hipStream_t s, int chunk, int k0, int kend, h16* terms, int ldT,
                       const int* rp, const int2* ep) {
    for (int k = (k0 == 0 ? 1 : k0); k < kend; ++k) {
        const h16* zb = terms + ((k - 1) % chunk) * 256;
        h16* db = terms + (k % chunk) * 256;
        if (k == 1) {
            spmv2<false><<<V_N / 4, 256, 0, s>>>(rp, ep, zb, nullptr, db, ldT);
        } else {
            const h16* pb = terms + ((k - 2) % chunk) * 256;
            spmv2<true><<<V_N / 4, 256, 0, s>>>(rp, ep, zb, pb, db, ldT);
        }
    }
}

extern "C" void kernel_launch(void* const* d_in, const int* in_sizes, int n_in,
                              void* d_out, int out_size, void* d_ws, size_t ws_size,
                              hipStream_t stream) {
    const float* x    = (const float*)d_in[0];
    const float* te   = (const float*)d_in[1];
    const int*   row  = (const int*)d_in[2];
    const int*   col  = (const int*)d_in[3];
    const float* vals = (const float*)d_in[4];
    const float* wres = (const float*)d_in[5];
    const float* w1   = (const float*)d_in[6];
    const float* w2   = (const float*)d_in[7];
    const float* g1   = (const float*)d_in[8];
    const float* b1   = (const float*)d_in[9];
    const float* g2   = (const float*)d_in[10];
    const float* b2   = (const float*)d_in[11];
    const float* wt   = (const float*)d_in[12];
    const float* bt   = (const float*)d_in[13];
    float* out = (float*)d_out;

    const size_t slot_b = (size_t)V_N * 256 * 2;          // 25.2 MB per k-slot
    const size_t res_b  = (size_t)V_N * 256 * 4;          // 50.3 MB
    const size_t csr_b  = (size_t)(V_N + V_N + 1) * 4 + (size_t)E_N * 8;
    const size_t wt_b   = (size_t)(1024 + 2048 + 1024) * CO * 2;
    const size_t misc_b = 8192 + (size_t)GN_BLOCKS * 16 * 4;
    auto need = [&](int ch) { return (size_t)ch * slot_b + res_b + csr_b + wt_b + misc_b; };
    // chunk=4 keeps the whole working set (terms 100MB + out 50 + res 50) LLC-resident
    int chunk = (ws_size >= need(4)) ? 4 : 2;
    if (ws_size < need(2)) return;
    const int ldT = chunk * 256;

    char* p = (char*)d_ws;
    h16* terms = (h16*)p;              p += (size_t)chunk * slot_b;
    float* resbuf = (float*)p;         p += res_b;
    h16* w1t = (h16*)p;                p += (size_t)1024 * CO * 2;
    h16* w2t = (h16*)p;                p += (size_t)2048 * CO * 2;
    h16* wrt = (h16*)p;                p += (size_t)1024 * CO * 2;
    int* cnt = (int*)p;                p += (size_t)V_N * 4;
    int* rp  = (int*)p;                p += (size_t)(V_N + 1) * 4;
    int2* ep = (int2*)p;               p += (size_t)E_N * 8;
    float* stats = (float*)p;          p += 64;
    float* tv = (float*)p;             p += 1024;
    float* gpart = (float*)p;          p += (size_t)GN_BLOCKS * 16 * 4;

    // CSR build
    hipMemsetAsync(cnt, 0, V_N * sizeof(int), stream);
    count_edges<<<E_N / 256, 256, 0, stream>>>(row, cnt);
    scan_rowptr<<<1, 1024, 0, stream>>>(cnt, rp);
    fill_csr<<<E_N / 256, 256, 0, stream>>>(row, col, vals, cnt, ep);

    // weight prep
    wprep<<<dim3(1024 / 16, 16), dim3(16, 16), 0, stream>>>(w1, w1t, 1024);
    wprep<<<dim3(2048 / 16, 16), dim3(16, 16), 0, stream>>>(w2, w2t, 2048);
    wprep<<<dim3(1024 / 16, 16), dim3(16, 16), 0, stream>>>(wres, wrt, 1024);

    // time embedding
    time_mlp<<<1, 256, 0, stream>>>(te, wt, bt, tv);

    // ---- GN1 + SiLU -> slot0 [gn | raw x] (merged conv1+res chain, C=256) ----
    gn_stats2<128><<<GN_BLOCKS, 256, 0, stream>>>(x, nullptr, gpart);
    gn_reduce<<<1, 256, 0, stream>>>(gpart, stats, GN_BLOCKS);
    gn1_apply<<<2048, 256, 0, stream>>>(x, stats, g1, b1, terms, ldT);

    // ---- merged chain: SpMV (C=256) + fused dual GEMM (conv1 gn-half, res x-half) ----
    for (int k0 = 0; k0 < 8; k0 += chunk) {
        int kend = (k0 + chunk < 8) ? k0 + chunk : 8;
        chain_spmv(stream, chunk, k0, kend, terms, ldT, rp, ep);
        int KC = (kend - k0) * 128;
        dim3 g(V_N / 64, 2);
        if (k0 == 0)
            gemm_f16<0, true><<<g, 256, 0, stream>>>(terms, ldT, w1t, wrt, 1024,
                                                     k0 * 128, KC, 7, nullptr, out, resbuf);
        else
            gemm_f16<1, true><<<g, 256, 0, stream>>>(terms, ldT, w1t, wrt, 1024,
                                                     k0 * 128, KC, 7, nullptr, out, resbuf);
    }

    // ---- GN2(h1 + tv) + SiLU -> terms slot0 (full 256) ----
    gn_stats2<256><<<GN_BLOCKS, 256, 0, stream>>>(out, tv, gpart);
    gn_reduce<<<1, 256, 0, stream>>>(gpart, stats, GN_BLOCKS);
    gn2_apply<<<2048, 256, 0, stream>>>(out, tv, stats, g2, b2, terms, ldT);

    // ---- conv2 chain: SpMV + GEMM; first GEMM fuses residual bias (no memcpy) ----
    for (int k0 = 0; k0 < 8; k0 += chunk) {
        int kend = (k0 + chunk < 8) ? k0 + chunk : 8;
        chain_spmv(stream, chunk, k0, kend, terms, ldT, rp, ep);
        int KC = (kend - k0) * 256;
        dim3 g(V_N / 64);
        if (k0 == 0)
            gemm_f16<2, false><<<g, 256, 0, stream>>>(terms, ldT, w2t, nullptr, 2048,
                                                      0, KC, 8, resbuf, out, nullptr);
        else
            gemm_f16<1, false><<<g, 256, 0, stream>>>(terms, ldT, w2t, nullptr, 2048,
                                                      k0 * 256, KC, 8, nullptr, out, nullptr);
    }
}